// Round 1
// baseline (578.497 us; speedup 1.0000x reference)
//
#include <hip/hip_runtime.h>
#include <cstdint>
#include <cstddef>

#define BN 4
#define CC 27
#define HH 160
#define WW 160
#define HWp (HH*WW)        // 25600
#define NPIX (BN*HWp)      // 102400
#define DD 768
#define KK 24
#define NSPLIT 16
#define DT 128

// ---- workspace float offsets ----
#define OFF_ACC 0                       // 32 scalars
#define OFF_S1 32                       // B*K*C = 2592
#define OFF_S2 (32+2592)
#define OFF_CNT (32+2592*2)             // 96
#define OFF_NSQ (32+2592*2+96)          // NPIX
#define ZERO_N (OFF_NSQ + NPIX)         // everything before here zeroed each call
#define OFF_LAB ZERO_N                  // uint8 region, NPIX bytes = NPIX/4 floats
#define OFF_PROBS (OFF_LAB + NPIX/4)
#define OFF_PT (OFF_PROBS + BN*CC*HWp)
#define OFF_PP (OFF_PT + BN*CC*HWp)     // NSPLIT*B*C*D
#define OFF_QP (OFF_PP + NSPLIT*BN*CC*DD)

// acc slots: 0 gsum, 1 distill, 2 bplnum, 3 bplcnt, 4 ent, 5 alignH, 6 alignV,
//            7 bceH(vert), 8 bceW(horiz), 9 proto

__device__ __forceinline__ float wave_sum(float v) {
#pragma unroll
  for (int o = 32; o > 0; o >>= 1) v += __shfl_down(v, o, 64);
  return v;
}

__global__ void k_zero(float* __restrict__ w, int n) {
  int i = blockIdx.x * 256 + threadIdx.x;
  if (i < n) w[i] = 0.f;
}

__global__ void k_depth_stats(const float* __restrict__ depth, float* __restrict__ acc) {
  int i = blockIdx.x * 256 + threadIdx.x;
  float g = 0.f;
  if (i < NPIX) {
    int b = i / HWp, r = i % HWp, h = r / WW, w = r % WW;
    const float* dp = depth + b * HWp;
    float d0 = dp[r];
    float gh = (h < HH-1) ? fabsf(dp[r+WW] - d0) : 0.f;
    float gw = (w < WW-1) ? fabsf(dp[r+1] - d0) : 0.f;
    g = gh + gw;
  }
  __shared__ float red;
  if (threadIdx.x == 0) red = 0.f;
  __syncthreads();
  float s = wave_sum(g);
  if ((threadIdx.x & 63) == 0) atomicAdd(&red, s);
  __syncthreads();
  if (threadIdx.x == 0) atomicAdd(&acc[0], red);
}

__global__ void k_labels(const float* __restrict__ cl, unsigned char* __restrict__ lab) {
  int i = blockIdx.x * 256 + threadIdx.x;
  if (i >= NPIX) return;
  int b = i / HWp, r = i % HWp;
  const float* p = cl + (size_t)b * CC * HWp + r;
  float best = p[0]; int bi = 0;
#pragma unroll
  for (int c = 1; c < CC; ++c) {
    float v = p[(size_t)c * HWp];
    if (v > best) { best = v; bi = c; }
  }
  lab[i] = (unsigned char)bi;
}

__global__ void k_main(const float* __restrict__ logits, const float* __restrict__ depth,
                       const unsigned char* __restrict__ lab, float* __restrict__ probs,
                       float* __restrict__ probs_t, float* __restrict__ acc) {
  int i = blockIdx.x * 256 + threadIdx.x;
  float c_dist = 0.f, c_bnum = 0.f, c_bcnt = 0.f, c_ent = 0.f;
  if (i < NPIX) {
    int b = i / HWp, r = i % HWp, h = r / WW, w = r % WW;
    const float* lg = logits + (size_t)b * CC * HWp + r;
    float x[CC];
    float m = -1e30f;
#pragma unroll
    for (int c = 0; c < CC; ++c) { x[c] = lg[(size_t)c * HWp]; m = fmaxf(m, x[c]); }
    float se = 0.f, sx = 0.f, set = 0.f;
#pragma unroll
    for (int c = 0; c < CC; ++c) {
      se += expf(x[c] - m);
      set += expf(10.f * (x[c] - m));
      sx += x[c];
    }
    float lse = logf(se);
    float inv_set = 1.f / set;
    int l = lab[i];
    float xl = x[0];
    float ent = 0.f;
    float* pb = probs + (size_t)b * CC * HWp + r;
    float* pt = probs_t + (size_t)b * CC * HWp + r;
#pragma unroll
    for (int c = 0; c < CC; ++c) {
      float lp = x[c] - m - lse;
      float p = expf(lp);
      pb[(size_t)c * HWp] = p;
      pt[(size_t)c * HWp] = expf(10.f * (x[c] - m)) * inv_set;
      ent -= p * lp;
      if (c == l) xl = x[c];
    }
    float nll = m + lse - xl;
    float ce = 0.8f * nll + 0.2f * (m + lse - sx * (1.f / CC));
    float ptf = expf(-ce);
    float wgt = (1.f - ptf) * (1.f - ptf);
    if (l >= 11 && l <= 18) wgt *= 2.f;
    const float* dp = depth + b * HWp;
    float d0 = dp[r];
    float gh = (h < HH-1) ? fabsf(dp[r+WW] - d0) : 0.f;
    float gw = (w < WW-1) ? fabsf(dp[r+1] - d0) : 0.f;
    float gmean = acc[0] * (1.f / NPIX);
    float gnorm = (gh + gw) / (gmean + 1e-6f);
    wgt *= 1.f + 0.1f * fminf(gnorm, 3.f);
    const unsigned char* lb = lab + b * HWp;
    int lL = lb[h*WW + (w>0 ? w-1 : w)];
    int lR = lb[h*WW + (w<WW-1 ? w+1 : w)];
    int lU = lb[(h>0 ? h-1 : h)*WW + w];
    int lD = lb[(h<HH-1 ? h+1 : h)*WW + w];
    float bnd = ((l != lL) | (l != lR) | (l != lU) | (l != lD)) ? 1.f : 0.f;
    c_dist = ce * wgt;
    c_bnum = ce * bnd;
    c_bcnt = bnd;
    c_ent = ent;
  }
  __shared__ float red[4];
  if (threadIdx.x < 4) red[threadIdx.x] = 0.f;
  __syncthreads();
  c_dist = wave_sum(c_dist); c_bnum = wave_sum(c_bnum);
  c_bcnt = wave_sum(c_bcnt); c_ent = wave_sum(c_ent);
  if ((threadIdx.x & 63) == 0) {
    atomicAdd(&red[0], c_dist); atomicAdd(&red[1], c_bnum);
    atomicAdd(&red[2], c_bcnt); atomicAdd(&red[3], c_ent);
  }
  __syncthreads();
  if (threadIdx.x == 0) {
    atomicAdd(&acc[1], red[0]); atomicAdd(&acc[2], red[1]);
    atomicAdd(&acc[3], red[2]); atomicAdd(&acc[4], red[3]);
  }
}

__global__ void k_featnorm(const float* __restrict__ feats, float* __restrict__ nsq) {
  int i = blockIdx.x * 256 + threadIdx.x;
  if (i >= NPIX) return;
  int b = i / HWp, r = i % HWp;
  int d0 = blockIdx.y * (DD / 4);
  const float* f = feats + ((size_t)b * DD + d0) * HWp + r;
  float s = 0.f;
#pragma unroll 8
  for (int d = 0; d < DD / 4; ++d) { float v = f[(size_t)d * HWp]; s += v * v; }
  atomicAdd(&nsq[i], s);
}

__global__ void __launch_bounds__(256) k_gemm(const float* __restrict__ feats,
        const float* __restrict__ probs_t, const float* __restrict__ nsq,
        float* __restrict__ pp, float* __restrict__ qp) {
  __shared__ float fbuf[64][128];      // [j][d] transposed: bank = d%32
  __shared__ float2 ptb[CC][64];       // (pt, pt*invnorm)
  int bx = blockIdx.x;
  int s = bx % NSPLIT;
  int dt = (bx / NSPLIT) % (DD / DT);
  int b = bx / (NSPLIT * (DD / DT));
  int t = threadIdx.x;
  int n0 = s * (HWp / NSPLIT);          // 1600 pixels per split
  const int NCH = (HWp / NSPLIT) / 64;  // 25 chunks
  int dg = t & 31, cg = t >> 5;
  float4 accP[4], accQ[4];
#pragma unroll
  for (int k = 0; k < 4; ++k) {
    accP[k] = make_float4(0.f, 0.f, 0.f, 0.f);
    accQ[k] = make_float4(0.f, 0.f, 0.f, 0.f);
  }
  int row = t >> 1, half = t & 1;
  const float* fr_base = feats + ((size_t)b * DD + dt * DT + row) * HWp + n0 + half * 32;
  const float* ptg = probs_t + (size_t)b * CC * HWp + n0;
  const float* nq = nsq + b * HWp + n0;
  for (int ch = 0; ch < NCH; ++ch) {
    if (ch) __syncthreads();
    const float4* fr = (const float4*)(fr_base + ch * 64);
#pragma unroll
    for (int q = 0; q < 8; ++q) {
      float4 v = fr[q];
      int j = half * 32 + q * 4;
      fbuf[j+0][row] = v.x; fbuf[j+1][row] = v.y;
      fbuf[j+2][row] = v.z; fbuf[j+3][row] = v.w;
    }
    for (int idx = t; idx < CC * 64; idx += 256) {
      int c = idx >> 6, j = idx & 63;
      float p = ptg[(size_t)c * HWp + ch * 64 + j];
      float ns = nq[ch * 64 + j];
      float inv = 1.f / fmaxf(sqrtf(ns), 1e-12f);
      ptb[c][j] = make_float2(p, p * inv);
    }
    __syncthreads();
#pragma unroll 4
    for (int j = 0; j < 64; ++j) {
      float4 f4 = *(const float4*)&fbuf[j][dg * 4];
#pragma unroll
      for (int k = 0; k < 4; ++k) {
        int c = cg + 8 * k;
        if (c < CC) {
          float2 w2 = ptb[c][j];
          accP[k].x += f4.x * w2.x; accP[k].y += f4.y * w2.x;
          accP[k].z += f4.z * w2.x; accP[k].w += f4.w * w2.x;
          accQ[k].x += f4.x * w2.y; accQ[k].y += f4.y * w2.y;
          accQ[k].z += f4.z * w2.y; accQ[k].w += f4.w * w2.y;
        }
      }
    }
  }
  size_t base = ((size_t)(s * BN + b) * CC) * DD + dt * DT + dg * 4;
#pragma unroll
  for (int k = 0; k < 4; ++k) {
    int c = cg + 8 * k;
    if (c < CC) {
      *(float4*)&pp[base + (size_t)c * DD] = accP[k];
      *(float4*)&qp[base + (size_t)c * DD] = accQ[k];
    }
  }
}

__global__ void k_align_ib(const float* __restrict__ probs, const float* __restrict__ depth,
                           const int* __restrict__ inst, float* __restrict__ acc) {
  int i = blockIdx.x * 256 + threadIdx.x;
  float aH = 0.f, aV = 0.f, bh = 0.f, bw = 0.f;
  if (i < NPIX) {
    int b = i / HWp, r = i % HWp, h = r / WW, w = r % WW;
    const float* P = probs + (size_t)b * CC * HWp + r;
    bool hasR = (w < WW-1), hasD = (h < HH-1);
    float sh = 0.f, sv = 0.f, mh = 0.f, mw = 0.f;
#pragma unroll
    for (int c = 0; c < CC; ++c) {
      float p  = P[(size_t)c * HWp];
      float pr = hasR ? P[(size_t)c * HWp + 1]  : p;
      float pd = hasD ? P[(size_t)c * HWp + WW] : p;
      float dr = pr - p, dd = pd - p;
      sh += dr * dr; sv += dd * dd;
      mw = fmaxf(mw, fabsf(dr)); mh = fmaxf(mh, fabsf(dd));
    }
    const float* dp = depth + b * HWp;
    const int* ip = inst + b * HWp;
    float d0 = dp[r];
    if (hasR) {
      float ddh = dp[r+1] - d0;
      aH = expf(-(ddh*ddh) * 200.f) * sh;   // 1/(2*sigma^2) = 200
      float y = (ip[r+1] != ip[r]) ? 1.f : 0.f;
      float xx = fminf(fmaxf(mw, 1e-6f), 1.f - 1e-6f);
      bw = -(y * logf(xx) + (1.f - y) * log1pf(-xx));
    }
    if (hasD) {
      float ddv = dp[r+WW] - d0;
      aV = expf(-(ddv*ddv) * 200.f) * sv;
      float y = (ip[r+WW] != ip[r]) ? 1.f : 0.f;
      float xx = fminf(fmaxf(mh, 1e-6f), 1.f - 1e-6f);
      bh = -(y * logf(xx) + (1.f - y) * log1pf(-xx));
    }
  }
  __shared__ float red[4];
  if (threadIdx.x < 4) red[threadIdx.x] = 0.f;
  __syncthreads();
  aH = wave_sum(aH); aV = wave_sum(aV); bh = wave_sum(bh); bw = wave_sum(bw);
  if ((threadIdx.x & 63) == 0) {
    atomicAdd(&red[0], aH); atomicAdd(&red[1], aV);
    atomicAdd(&red[2], bh); atomicAdd(&red[3], bw);
  }
  __syncthreads();
  if (threadIdx.x == 0) {
    atomicAdd(&acc[5], red[0]); atomicAdd(&acc[6], red[1]);
    atomicAdd(&acc[7], red[2]); atomicAdd(&acc[8], red[3]);
  }
}

__global__ void k_iu(const float* __restrict__ probs, const int* __restrict__ inst,
                     float* __restrict__ s1g, float* __restrict__ s2g, float* __restrict__ cntg) {
  __shared__ float ls1[KK*CC], ls2[KK*CC], lc[KK];
  int t = threadIdx.x;
  for (int idx = t; idx < KK*CC; idx += 256) { ls1[idx] = 0.f; ls2[idx] = 0.f; }
  if (t < KK) lc[t] = 0.f;
  __syncthreads();
  int b = blockIdx.x / (HWp / 512);
  int seg = blockIdx.x % (HWp / 512);
  int base = seg * 512;
#pragma unroll
  for (int q = 0; q < 2; ++q) {
    int n = base + q * 256 + t;
    int id = inst[b * HWp + n];
    const float* P = probs + (size_t)b * CC * HWp + n;
    atomicAdd(&lc[id], 1.f);
#pragma unroll
    for (int c = 0; c < CC; ++c) {
      float p = P[(size_t)c * HWp];
      atomicAdd(&ls1[id*CC + c], p);
      atomicAdd(&ls2[id*CC + c], p * p);
    }
  }
  __syncthreads();
  for (int idx = t; idx < KK*CC; idx += 256) {
    atomicAdd(&s1g[b*KK*CC + idx], ls1[idx]);
    atomicAdd(&s2g[b*KK*CC + idx], ls2[idx]);
  }
  if (t < KK) atomicAdd(&cntg[b*KK + t], lc[t]);
}

__global__ void k_pfinal(const float* __restrict__ pp, const float* __restrict__ qp,
                         float* __restrict__ acc) {
  int bc = blockIdx.x; int b = bc / CC; int c = bc % CC;
  float dot = 0.f, nsq = 0.f;
  for (int d = threadIdx.x; d < DD; d += 256) {
    float p = 0.f, q = 0.f;
#pragma unroll
    for (int s = 0; s < NSPLIT; ++s) {
      size_t off = ((size_t)(s * BN + b) * CC + c) * DD + d;
      p += pp[off]; q += qp[off];
    }
    dot += p * q; nsq += p * p;
  }
  __shared__ float red[2];
  if (threadIdx.x < 2) red[threadIdx.x] = 0.f;
  __syncthreads();
  dot = wave_sum(dot); nsq = wave_sum(nsq);
  if ((threadIdx.x & 63) == 0) { atomicAdd(&red[0], dot); atomicAdd(&red[1], nsq); }
  __syncthreads();
  if (threadIdx.x == 0) atomicAdd(&acc[9], red[0] / fmaxf(sqrtf(red[1]), 1e-12f));
}

__global__ void k_final(const float* __restrict__ s1g, const float* __restrict__ s2g,
                        const float* __restrict__ cntg, const float* __restrict__ acc,
                        float* __restrict__ out) {
  int t = threadIdx.x;
  float vsum = 0.f, vcnt = 0.f;
  if (t < BN*KK) {
    int k = t % KK;
    float count = cntg[t];
    float nc = fmaxf(count, 1.f);
    float var = 0.f;
#pragma unroll
    for (int c = 0; c < CC; ++c) {
      float m1 = s1g[t*CC + c] / nc;
      var += s2g[t*CC + c] / nc - m1 * m1;
    }
    var *= (1.f / CC);
    if (k > 0 && count >= 25.f) { vsum = var; vcnt = 1.f; }
  }
  __shared__ float red[2];
  if (t < 2) red[t] = 0.f;
  __syncthreads();
  vsum = wave_sum(vsum); vcnt = wave_sum(vcnt);
  if ((t & 63) == 0) { atomicAdd(&red[0], vsum); atomicAdd(&red[1], vcnt); }
  __syncthreads();
  if (t == 0) {
    float l_distill = acc[1] * (1.f / NPIX);
    float bcnt = acc[3];
    float l_bpl = (bcnt > 0.f) ? acc[2] / fmaxf(bcnt, 1.f) : 0.f;
    float l_align = acc[5] * (1.f / (BN*HH*(WW-1))) + acc[6] * (1.f / (BN*(HH-1)*WW));
    float l_ent = acc[4] * (1.f / NPIX);
    float l_ib = 0.5f * (acc[7] * (1.f / (BN*(HH-1)*WW)) + acc[8] * (1.f / (BN*HH*(WW-1))));
    float l_proto = -acc[9] * (1.f / NPIX);
    float l_iu = red[0] / fmaxf(red[1], 1.f);
    out[0] = 1.0f*l_distill + 0.5f*l_bpl + 5.0f*l_align + 0.5f*l_proto +
             0.3f*l_ent + 0.5f*l_iu + 0.5f*l_ib;
  }
}

extern "C" void kernel_launch(void* const* d_in, const int* in_sizes, int n_in,
                              void* d_out, int out_size, void* d_ws, size_t ws_size,
                              hipStream_t stream) {
  (void)in_sizes; (void)n_in; (void)out_size; (void)ws_size;
  const float* logits = (const float*)d_in[0];
  const float* cause  = (const float*)d_in[1];
  const float* feats  = (const float*)d_in[2];
  const float* depth  = (const float*)d_in[3];
  const int*   inst   = (const int*)d_in[4];
  float* ws = (float*)d_ws;
  float* acc = ws + OFF_ACC;
  float* s1  = ws + OFF_S1;
  float* s2  = ws + OFF_S2;
  float* cnt = ws + OFF_CNT;
  float* nsq = ws + OFF_NSQ;
  unsigned char* lab = (unsigned char*)(ws + OFF_LAB);
  float* probs   = ws + OFF_PROBS;
  float* probs_t = ws + OFF_PT;
  float* pp = ws + OFF_PP;
  float* qp = ws + OFF_QP;
  float* out = (float*)d_out;

  k_zero<<<(ZERO_N + 255) / 256, 256, 0, stream>>>(ws, ZERO_N);
  k_depth_stats<<<NPIX / 256, 256, 0, stream>>>(depth, acc);
  k_labels<<<NPIX / 256, 256, 0, stream>>>(cause, lab);
  k_main<<<NPIX / 256, 256, 0, stream>>>(logits, depth, lab, probs, probs_t, acc);
  k_featnorm<<<dim3(NPIX / 256, 4), 256, 0, stream>>>(feats, nsq);
  k_gemm<<<BN * (DD / DT) * NSPLIT, 256, 0, stream>>>(feats, probs_t, nsq, pp, qp);
  k_align_ib<<<NPIX / 256, 256, 0, stream>>>(probs, depth, inst, acc);
  k_iu<<<BN * (HWp / 512), 256, 0, stream>>>(probs, inst, s1, s2, cnt);
  k_pfinal<<<BN * CC, 256, 0, stream>>>(pp, qp, acc);
  k_final<<<1, 256, 0, stream>>>(s1, s2, cnt, acc, out);
}

// Round 2
// 321.893 us; speedup vs baseline: 1.7972x; 1.7972x over previous
//
#include <hip/hip_runtime.h>
#include <cstdint>
#include <cstddef>

#define BN 4
#define CC 27
#define HH 160
#define WW 160
#define HWp (HH*WW)        // 25600
#define NPIX (BN*HWp)      // 102400
#define DD 768
#define KK 24
#define NSPLIT 40
#define SPX (HWp/NSPLIT)   // 640 px per split
#define NCH (SPX/64)       // 10 chunks of 64 px

// ---- workspace float offsets ----
#define OFF_ACC 0                       // 32 scalars
#define OFF_S1 32                       // B*K*C = 2592
#define OFF_S2 (32+2592)
#define OFF_CNT (32+2592*2)             // 96
#define OFF_NSQ (32+2592*2+96)          // NPIX
#define OFF_PP (OFF_NSQ + NPIX)         // B*CC*DD = 82944 (P accum)
#define OFF_QP (OFF_PP + BN*CC*DD)      // B*CC*DD (Q accum)
#define ZERO_N (OFF_QP + BN*CC*DD)      // everything before here zeroed each call
#define OFF_LAB ZERO_N                  // uint8 region, NPIX bytes = NPIX/4 floats
#define OFF_PROBS (OFF_LAB + NPIX/4)
#define OFF_PT (OFF_PROBS + BN*CC*HWp)

// acc slots: 0 gsum, 1 distill, 2 bplnum, 3 bplcnt, 4 ent, 5 alignH, 6 alignV,
//            7 bceH(vert), 8 bceW(horiz), 9 proto

typedef __attribute__((ext_vector_type(8))) short short8v;
typedef __attribute__((ext_vector_type(4))) float f32x4;

__device__ __forceinline__ float wave_sum(float v) {
#pragma unroll
  for (int o = 32; o > 0; o >>= 1) v += __shfl_down(v, o, 64);
  return v;
}

__device__ __forceinline__ short f2bf(float x) {
  unsigned u = __builtin_bit_cast(unsigned, x);
  unsigned r = u + 0x7FFFu + ((u >> 16) & 1u);
  return (short)(r >> 16);
}

__global__ void k_zero(float* __restrict__ w, int n) {
  int i = blockIdx.x * 256 + threadIdx.x;
  if (i < n) w[i] = 0.f;
}

__global__ void k_depth_stats(const float* __restrict__ depth, float* __restrict__ acc) {
  int i = blockIdx.x * 256 + threadIdx.x;
  float g = 0.f;
  if (i < NPIX) {
    int b = i / HWp, r = i % HWp, h = r / WW, w = r % WW;
    const float* dp = depth + b * HWp;
    float d0 = dp[r];
    float gh = (h < HH-1) ? fabsf(dp[r+WW] - d0) : 0.f;
    float gw = (w < WW-1) ? fabsf(dp[r+1] - d0) : 0.f;
    g = gh + gw;
  }
  __shared__ float red;
  if (threadIdx.x == 0) red = 0.f;
  __syncthreads();
  float s = wave_sum(g);
  if ((threadIdx.x & 63) == 0) atomicAdd(&red, s);
  __syncthreads();
  if (threadIdx.x == 0) atomicAdd(&acc[0], red);
}

__global__ void k_labels(const float* __restrict__ cl, unsigned char* __restrict__ lab) {
  int i = blockIdx.x * 256 + threadIdx.x;
  if (i >= NPIX) return;
  int b = i / HWp, r = i % HWp;
  const float* p = cl + (size_t)b * CC * HWp + r;
  float best = p[0]; int bi = 0;
#pragma unroll
  for (int c = 1; c < CC; ++c) {
    float v = p[(size_t)c * HWp];
    if (v > best) { best = v; bi = c; }
  }
  lab[i] = (unsigned char)bi;
}

__global__ void k_main(const float* __restrict__ logits, const float* __restrict__ depth,
                       const unsigned char* __restrict__ lab, float* __restrict__ probs,
                       float* __restrict__ probs_t, float* __restrict__ acc) {
  int i = blockIdx.x * 256 + threadIdx.x;
  float c_dist = 0.f, c_bnum = 0.f, c_bcnt = 0.f, c_ent = 0.f;
  if (i < NPIX) {
    int b = i / HWp, r = i % HWp, h = r / WW, w = r % WW;
    const float* lg = logits + (size_t)b * CC * HWp + r;
    float x[CC];
    float m = -1e30f;
#pragma unroll
    for (int c = 0; c < CC; ++c) { x[c] = lg[(size_t)c * HWp]; m = fmaxf(m, x[c]); }
    float se = 0.f, sx = 0.f, set = 0.f;
#pragma unroll
    for (int c = 0; c < CC; ++c) {
      se += expf(x[c] - m);
      set += expf(10.f * (x[c] - m));
      sx += x[c];
    }
    float lse = logf(se);
    float inv_set = 1.f / set;
    int l = lab[i];
    float xl = x[0];
    float ent = 0.f;
    float* pb = probs + (size_t)b * CC * HWp + r;
    float* pt = probs_t + (size_t)b * CC * HWp + r;
#pragma unroll
    for (int c = 0; c < CC; ++c) {
      float lp = x[c] - m - lse;
      float p = expf(lp);
      pb[(size_t)c * HWp] = p;
      pt[(size_t)c * HWp] = expf(10.f * (x[c] - m)) * inv_set;
      ent -= p * lp;
      if (c == l) xl = x[c];
    }
    float nll = m + lse - xl;
    float ce = 0.8f * nll + 0.2f * (m + lse - sx * (1.f / CC));
    float ptf = expf(-ce);
    float wgt = (1.f - ptf) * (1.f - ptf);
    if (l >= 11 && l <= 18) wgt *= 2.f;
    const float* dp = depth + b * HWp;
    float d0 = dp[r];
    float gh = (h < HH-1) ? fabsf(dp[r+WW] - d0) : 0.f;
    float gw = (w < WW-1) ? fabsf(dp[r+1] - d0) : 0.f;
    float gmean = acc[0] * (1.f / NPIX);
    float gnorm = (gh + gw) / (gmean + 1e-6f);
    wgt *= 1.f + 0.1f * fminf(gnorm, 3.f);
    const unsigned char* lb = lab + b * HWp;
    int lL = lb[h*WW + (w>0 ? w-1 : w)];
    int lR = lb[h*WW + (w<WW-1 ? w+1 : w)];
    int lU = lb[(h>0 ? h-1 : h)*WW + w];
    int lD = lb[(h<HH-1 ? h+1 : h)*WW + w];
    float bnd = ((l != lL) | (l != lR) | (l != lU) | (l != lD)) ? 1.f : 0.f;
    c_dist = ce * wgt;
    c_bnum = ce * bnd;
    c_bcnt = bnd;
    c_ent = ent;
  }
  __shared__ float red[4];
  if (threadIdx.x < 4) red[threadIdx.x] = 0.f;
  __syncthreads();
  c_dist = wave_sum(c_dist); c_bnum = wave_sum(c_bnum);
  c_bcnt = wave_sum(c_bcnt); c_ent = wave_sum(c_ent);
  if ((threadIdx.x & 63) == 0) {
    atomicAdd(&red[0], c_dist); atomicAdd(&red[1], c_bnum);
    atomicAdd(&red[2], c_bcnt); atomicAdd(&red[3], c_ent);
  }
  __syncthreads();
  if (threadIdx.x == 0) {
    atomicAdd(&acc[1], red[0]); atomicAdd(&acc[2], red[1]);
    atomicAdd(&acc[3], red[2]); atomicAdd(&acc[4], red[3]);
  }
}

__global__ void k_featnorm(const float* __restrict__ feats, float* __restrict__ nsq) {
  int i = blockIdx.x * 256 + threadIdx.x;
  if (i >= NPIX) return;
  int b = i / HWp, r = i % HWp;
  int d0 = blockIdx.y * (DD / 4);
  const float* f = feats + ((size_t)b * DD + d0) * HWp + r;
  float s = 0.f;
#pragma unroll 8
  for (int d = 0; d < DD / 4; ++d) { float v = f[(size_t)d * HWp]; s += v * v; }
  atomicAdd(&nsq[i], s);
}

// MFMA GEMM: per block (b, dt, s) computes a [128 x 64] tile of
//   P[d,c']  = sum_n fbf[d,n] * W[c',n]
// with W[c',n] = pt[c',n] for c'<32 (c'<27 real), pt[c'-32,n]*invnorm[n] for c'>=32.
// Accumulated across s-splits via global fp32 atomicAdd into P/Q [b][c][d].
__global__ void __launch_bounds__(256) k_gemm(const float* __restrict__ feats,
        const float* __restrict__ probs_t, const float* __restrict__ nsq,
        float* __restrict__ P, float* __restrict__ Q) {
  __shared__ short As[128 * 64];   // [row d][64 bf16], 16B chunks XOR-swizzled
  __shared__ short Ws[64 * 64];    // [row c'][64 bf16], same swizzle
  int bx = blockIdx.x;
  int s  = bx % NSPLIT;
  int dt = (bx / NSPLIT) % (DD / 128);
  int b  = bx / (NSPLIT * (DD / 128));
  int t = threadIdx.x;
  int wave = t >> 6, lane = t & 63;
  int g = lane >> 4, rr = lane & 15;
  f32x4 acc[2][4] = {};
  int n0 = s * SPX;
  const float* fbase  = feats   + ((size_t)b * DD + dt * 128) * HWp + n0;
  const float* ptbase = probs_t + (size_t)b * CC * HWp + n0;
  const float* nqbase = nsq     + (size_t)b * HWp + n0;

  for (int ch = 0; ch < NCH; ++ch) {
    if (ch) __syncthreads();
    // ---- stage A: 128 rows x 8 chunks (8 fp32 -> 8 bf16 = 16B each), 4/thread
#pragma unroll
    for (int it = 0; it < 4; ++it) {
      int idx = it * 256 + t;
      int row = idx >> 3, cki = idx & 7;
      const float* src = fbase + (size_t)row * HWp + ch * 64 + cki * 8;
      float4 v0 = *(const float4*)src;
      float4 v1 = *(const float4*)(src + 4);
      short8v h;
      h[0]=f2bf(v0.x); h[1]=f2bf(v0.y); h[2]=f2bf(v0.z); h[3]=f2bf(v0.w);
      h[4]=f2bf(v1.x); h[5]=f2bf(v1.y); h[6]=f2bf(v1.z); h[7]=f2bf(v1.w);
      int pck = cki ^ (row & 7);
      *(short8v*)&As[row * 64 + pck * 8] = h;
    }
    // ---- stage W: 64 rows x 8 chunks, 2/thread
#pragma unroll
    for (int it = 0; it < 2; ++it) {
      int idx = it * 256 + t;
      int row = idx >> 3, cki = idx & 7;   // row = c'
      short8v h;
      int c = row & 31;
      if (c < CC) {
        const float* sp = ptbase + (size_t)c * HWp + ch * 64 + cki * 8;
        float4 v0 = *(const float4*)sp;
        float4 v1 = *(const float4*)(sp + 4);
        float wv[8] = {v0.x, v0.y, v0.z, v0.w, v1.x, v1.y, v1.z, v1.w};
        if (row >= 32) {
          const float* nq = nqbase + ch * 64 + cki * 8;
          float4 n0v = *(const float4*)nq;
          float4 n1v = *(const float4*)(nq + 4);
          float nv[8] = {n0v.x, n0v.y, n0v.z, n0v.w, n1v.x, n1v.y, n1v.z, n1v.w};
#pragma unroll
          for (int j = 0; j < 8; ++j) wv[j] *= 1.f / fmaxf(sqrtf(nv[j]), 1e-12f);
        }
#pragma unroll
        for (int j = 0; j < 8; ++j) h[j] = f2bf(wv[j]);
      } else {
#pragma unroll
        for (int j = 0; j < 8; ++j) h[j] = 0;
      }
      int pck = cki ^ (row & 7);
      *(short8v*)&Ws[row * 64 + pck * 8] = h;
    }
    __syncthreads();
    // ---- MFMA: 2 K-steps of 32 px
#pragma unroll
    for (int ks = 0; ks < 2; ++ks) {
      short8v a[2], wf[4];
#pragma unroll
      for (int dd = 0; dd < 2; ++dd) {
        int row = (wave * 2 + dd) * 16 + rr;
        int ck = (ks * 4 + g) ^ (row & 7);
        a[dd] = *(const short8v*)&As[row * 64 + ck * 8];
      }
#pragma unroll
      for (int ct = 0; ct < 4; ++ct) {
        int row = ct * 16 + rr;
        int ck = (ks * 4 + g) ^ (row & 7);
        wf[ct] = *(const short8v*)&Ws[row * 64 + ck * 8];
      }
#pragma unroll
      for (int dd = 0; dd < 2; ++dd)
#pragma unroll
        for (int ct = 0; ct < 4; ++ct)
          acc[dd][ct] = __builtin_amdgcn_mfma_f32_16x16x32_bf16(a[dd], wf[ct], acc[dd][ct], 0, 0, 0);
    }
  }
  // ---- epilogue: C/D layout col=lane&15, row=(lane>>4)*4+reg
#pragma unroll
  for (int dd = 0; dd < 2; ++dd) {
#pragma unroll
    for (int ct = 0; ct < 4; ++ct) {
      int cp = ct * 16 + rr;
#pragma unroll
      for (int rg = 0; rg < 4; ++rg) {
        int d = dt * 128 + (wave * 2 + dd) * 16 + g * 4 + rg;
        float v = acc[dd][ct][rg];
        if (cp < CC)
          atomicAdd(&P[((size_t)b * CC + cp) * DD + d], v);
        else if (cp >= 32 && cp < 32 + CC)
          atomicAdd(&Q[((size_t)b * CC + (cp - 32)) * DD + d], v);
      }
    }
  }
}

__global__ void k_align_ib(const float* __restrict__ probs, const float* __restrict__ depth,
                           const int* __restrict__ inst, float* __restrict__ acc) {
  int i = blockIdx.x * 256 + threadIdx.x;
  float aH = 0.f, aV = 0.f, bh = 0.f, bw = 0.f;
  if (i < NPIX) {
    int b = i / HWp, r = i % HWp, h = r / WW, w = r % WW;
    const float* P = probs + (size_t)b * CC * HWp + r;
    bool hasR = (w < WW-1), hasD = (h < HH-1);
    float sh = 0.f, sv = 0.f, mh = 0.f, mw = 0.f;
#pragma unroll
    for (int c = 0; c < CC; ++c) {
      float p  = P[(size_t)c * HWp];
      float pr = hasR ? P[(size_t)c * HWp + 1]  : p;
      float pd = hasD ? P[(size_t)c * HWp + WW] : p;
      float dr = pr - p, dd = pd - p;
      sh += dr * dr; sv += dd * dd;
      mw = fmaxf(mw, fabsf(dr)); mh = fmaxf(mh, fabsf(dd));
    }
    const float* dp = depth + b * HWp;
    const int* ip = inst + b * HWp;
    float d0 = dp[r];
    if (hasR) {
      float ddh = dp[r+1] - d0;
      aH = expf(-(ddh*ddh) * 200.f) * sh;
      float y = (ip[r+1] != ip[r]) ? 1.f : 0.f;
      float xx = fminf(fmaxf(mw, 1e-6f), 1.f - 1e-6f);
      bw = -(y * logf(xx) + (1.f - y) * log1pf(-xx));
    }
    if (hasD) {
      float ddv = dp[r+WW] - d0;
      aV = expf(-(ddv*ddv) * 200.f) * sv;
      float y = (ip[r+WW] != ip[r]) ? 1.f : 0.f;
      float xx = fminf(fmaxf(mh, 1e-6f), 1.f - 1e-6f);
      bh = -(y * logf(xx) + (1.f - y) * log1pf(-xx));
    }
  }
  __shared__ float red[4];
  if (threadIdx.x < 4) red[threadIdx.x] = 0.f;
  __syncthreads();
  aH = wave_sum(aH); aV = wave_sum(aV); bh = wave_sum(bh); bw = wave_sum(bw);
  if ((threadIdx.x & 63) == 0) {
    atomicAdd(&red[0], aH); atomicAdd(&red[1], aV);
    atomicAdd(&red[2], bh); atomicAdd(&red[3], bw);
  }
  __syncthreads();
  if (threadIdx.x == 0) {
    atomicAdd(&acc[5], red[0]); atomicAdd(&acc[6], red[1]);
    atomicAdd(&acc[7], red[2]); atomicAdd(&acc[8], red[3]);
  }
}

__global__ void k_iu(const float* __restrict__ probs, const int* __restrict__ inst,
                     float* __restrict__ s1g, float* __restrict__ s2g, float* __restrict__ cntg) {
  __shared__ float ls1[KK*CC], ls2[KK*CC], lc[KK];
  int t = threadIdx.x;
  for (int idx = t; idx < KK*CC; idx += 256) { ls1[idx] = 0.f; ls2[idx] = 0.f; }
  if (t < KK) lc[t] = 0.f;
  __syncthreads();
  int b = blockIdx.x / (HWp / 512);
  int seg = blockIdx.x % (HWp / 512);
  int base = seg * 512;
#pragma unroll
  for (int q = 0; q < 2; ++q) {
    int n = base + q * 256 + t;
    int id = inst[b * HWp + n];
    const float* P = probs + (size_t)b * CC * HWp + n;
    atomicAdd(&lc[id], 1.f);
#pragma unroll
    for (int c = 0; c < CC; ++c) {
      float p = P[(size_t)c * HWp];
      atomicAdd(&ls1[id*CC + c], p);
      atomicAdd(&ls2[id*CC + c], p * p);
    }
  }
  __syncthreads();
  for (int idx = t; idx < KK*CC; idx += 256) {
    atomicAdd(&s1g[b*KK*CC + idx], ls1[idx]);
    atomicAdd(&s2g[b*KK*CC + idx], ls2[idx]);
  }
  if (t < KK) atomicAdd(&cntg[b*KK + t], lc[t]);
}

__global__ void k_pfinal(const float* __restrict__ P, const float* __restrict__ Q,
                         float* __restrict__ acc) {
  int bc = blockIdx.x;   // b*CC + c
  float dot = 0.f, nsq = 0.f;
  for (int d = threadIdx.x; d < DD; d += 256) {
    float p = P[(size_t)bc * DD + d];
    float q = Q[(size_t)bc * DD + d];
    dot += p * q; nsq += p * p;
  }
  __shared__ float red[2];
  if (threadIdx.x < 2) red[threadIdx.x] = 0.f;
  __syncthreads();
  dot = wave_sum(dot); nsq = wave_sum(nsq);
  if ((threadIdx.x & 63) == 0) { atomicAdd(&red[0], dot); atomicAdd(&red[1], nsq); }
  __syncthreads();
  if (threadIdx.x == 0) atomicAdd(&acc[9], red[0] / fmaxf(sqrtf(red[1]), 1e-12f));
}

__global__ void k_final(const float* __restrict__ s1g, const float* __restrict__ s2g,
                        const float* __restrict__ cntg, const float* __restrict__ acc,
                        float* __restrict__ out) {
  int t = threadIdx.x;
  float vsum = 0.f, vcnt = 0.f;
  if (t < BN*KK) {
    int k = t % KK;
    float count = cntg[t];
    float nc = fmaxf(count, 1.f);
    float var = 0.f;
#pragma unroll
    for (int c = 0; c < CC; ++c) {
      float m1 = s1g[t*CC + c] / nc;
      var += s2g[t*CC + c] / nc - m1 * m1;
    }
    var *= (1.f / CC);
    if (k > 0 && count >= 25.f) { vsum = var; vcnt = 1.f; }
  }
  __shared__ float red[2];
  if (t < 2) red[t] = 0.f;
  __syncthreads();
  vsum = wave_sum(vsum); vcnt = wave_sum(vcnt);
  if ((t & 63) == 0) { atomicAdd(&red[0], vsum); atomicAdd(&red[1], vcnt); }
  __syncthreads();
  if (t == 0) {
    float l_distill = acc[1] * (1.f / NPIX);
    float bcnt = acc[3];
    float l_bpl = (bcnt > 0.f) ? acc[2] / fmaxf(bcnt, 1.f) : 0.f;
    float l_align = acc[5] * (1.f / (BN*HH*(WW-1))) + acc[6] * (1.f / (BN*(HH-1)*WW));
    float l_ent = acc[4] * (1.f / NPIX);
    float l_ib = 0.5f * (acc[7] * (1.f / (BN*(HH-1)*WW)) + acc[8] * (1.f / (BN*HH*(WW-1))));
    float l_proto = -acc[9] * (1.f / NPIX);
    float l_iu = red[0] / fmaxf(red[1], 1.f);
    out[0] = 1.0f*l_distill + 0.5f*l_bpl + 5.0f*l_align + 0.5f*l_proto +
             0.3f*l_ent + 0.5f*l_iu + 0.5f*l_ib;
  }
}

extern "C" void kernel_launch(void* const* d_in, const int* in_sizes, int n_in,
                              void* d_out, int out_size, void* d_ws, size_t ws_size,
                              hipStream_t stream) {
  (void)in_sizes; (void)n_in; (void)out_size; (void)ws_size;
  const float* logits = (const float*)d_in[0];
  const float* cause  = (const float*)d_in[1];
  const float* feats  = (const float*)d_in[2];
  const float* depth  = (const float*)d_in[3];
  const int*   inst   = (const int*)d_in[4];
  float* ws = (float*)d_ws;
  float* acc = ws + OFF_ACC;
  float* s1  = ws + OFF_S1;
  float* s2  = ws + OFF_S2;
  float* cnt = ws + OFF_CNT;
  float* nsq = ws + OFF_NSQ;
  float* Pg  = ws + OFF_PP;
  float* Qg  = ws + OFF_QP;
  unsigned char* lab = (unsigned char*)(ws + OFF_LAB);
  float* probs   = ws + OFF_PROBS;
  float* probs_t = ws + OFF_PT;
  float* out = (float*)d_out;

  k_zero<<<(ZERO_N + 255) / 256, 256, 0, stream>>>(ws, ZERO_N);
  k_depth_stats<<<NPIX / 256, 256, 0, stream>>>(depth, acc);
  k_labels<<<NPIX / 256, 256, 0, stream>>>(cause, lab);
  k_main<<<NPIX / 256, 256, 0, stream>>>(logits, depth, lab, probs, probs_t, acc);
  k_featnorm<<<dim3(NPIX / 256, 4), 256, 0, stream>>>(feats, nsq);
  k_gemm<<<BN * (DD / 128) * NSPLIT, 256, 0, stream>>>(feats, probs_t, nsq, Pg, Qg);
  k_align_ib<<<NPIX / 256, 256, 0, stream>>>(probs, depth, inst, acc);
  k_iu<<<BN * (HWp / 512), 256, 0, stream>>>(probs, inst, s1, s2, cnt);
  k_pfinal<<<BN * CC, 256, 0, stream>>>(Pg, Qg, acc);
  k_final<<<1, 256, 0, stream>>>(s1, s2, cnt, acc, out);
}